// Round 12
// baseline (347.497 us; speedup 1.0000x reference)
//
#include <hip/hip_runtime.h>

#define NN 100000
#define NE 1600000
#define HD 128
#define IND 20
#define LNEPS 1e-5f
#define NLIST2 400000   // 4 type regions of NN
#define NBKT 3125       // dst>>5 buckets == k_fused blocks
#define PASSA_B 256     // FILL_B==PASSA_B sets scatter parallelism (round-10 lesson)
#define EDGES_PER_B 6250
#define FILL_B 256
#define WCAT_B 512
#define WCATE_B 256
#define W1P_B 128       // enc-W1 expanded-K pack role blocks
#define FILLN_B 400
#define ENC_B 12500
#define ASTRIDE 260     // A-tile row stride in 32-bit words (520 bf16)
#define SORT_CAP 4096
#define PAD_PER_BKT 672 // 96 segments * up to 7 pad each (seg pad-to-8)
#define NEP (NE + NBKT * PAD_PER_BKT)
#define H1S 136         // enc h1 row stride in bf16 (272 B, 16B-aligned rows)
#define AES 72          // enc expanded-A row stride in bf16 (144 B, 16B-aligned rows)

typedef unsigned int uint32;
typedef unsigned short ushort16;
typedef __attribute__((ext_vector_type(8))) short bf16x8;
typedef __attribute__((ext_vector_type(4))) float f32x4;
typedef __attribute__((ext_vector_type(2))) float f32x2;

__device__ __forceinline__ ushort16 f2bf(float f) {
    uint32 u = __float_as_uint(f);
    u += 0x7fffu + ((u >> 16) & 1u);   // round-to-nearest-even
    return (ushort16)(u >> 16);
}
__device__ __forceinline__ float bf2f1(ushort16 h) {
    return __uint_as_float(((uint32)h) << 16);
}
__device__ __forceinline__ uint32 pack2bf(float2 v) {
    return (uint32)f2bf(v.x) | ((uint32)f2bf(v.y) << 16);
}

// ---------------- pass A: bucket histogram | enc-W2 pack | enc-W1 pack | node list ----------
// Node-list role uses BLOCK-BATCHED atomics (round-5 fix).

__global__ __launch_bounds__(256) void k_hist(const int* __restrict__ ei,
                                              const int* __restrict__ et,
                                              int* __restrict__ H,
                                              ushort16* __restrict__ key16,
                                              unsigned* __restrict__ hdr32,
                                              const float* __restrict__ W2,
                                              ushort16* __restrict__ Weh,
                                              ushort16* __restrict__ Wel,
                                              const float* __restrict__ W1,
                                              ushort16* __restrict__ W1e,
                                              const int* __restrict__ nt,
                                              int* misc, unsigned* nodelist,
                                              uint32* x0, uint32* x1) {
    __shared__ int hist[NBKT];
    __shared__ int cnt4[4][4];   // [wave][type] node-list role
    __shared__ int base4[4];     // block base per type
    int bid = blockIdx.x, tid = threadIdx.x;

    if (bid >= PASSA_B + WCATE_B + W1P_B) {
        // ---- node list (block-batched atomics) + zero sentinel rows ----
        int rb = bid - PASSA_B - WCATE_B - W1P_B;
        int lane = tid & 63;
        int w = tid >> 6;
        if (rb == 0 && tid < 32) {     // zero row NN of both x buffers
            x0[(size_t)NN * 32 + tid] = 0;
            x1[(size_t)NN * 32 + tid] = 0;
        }
        int i = rb * 256 + tid;        // 400*256 = 102400 >= NN: single step
        int t = (i < NN) ? nt[i] : -1;
        unsigned long long lt = ((unsigned long long)1 << lane) - 1;
        int pre[4], wc[4];
#pragma unroll
        for (int tt = 0; tt < 4; tt++) {
            unsigned long long m = __ballot(t == tt);
            pre[tt] = (int)__popcll(m & lt);
            wc[tt] = (int)__popcll(m);
        }
        if (lane == 0) {
            cnt4[w][0] = wc[0]; cnt4[w][1] = wc[1];
            cnt4[w][2] = wc[2]; cnt4[w][3] = wc[3];
        }
        __syncthreads();
        if (tid < 4) {   // 4 PARALLEL atomics per block (one per type)
            int tot = cnt4[0][tid] + cnt4[1][tid] + cnt4[2][tid] + cnt4[3][tid];
            base4[tid] = tot ? atomicAdd(&misc[8 + tid], tot) : 0;
        }
        __syncthreads();
        if (t >= 0) {
            int off = base4[t] + pre[t];
#pragma unroll
            for (int wp = 0; wp < 3; wp++) if (wp < w) off += cnt4[wp][t];
            nodelist[t * NN + off] = (unsigned)i | ((unsigned)t << 17);
        }
        return;
    }
    if (bid >= PASSA_B + WCATE_B) {
        // ---- enc W1 -> tripled-K (hi,hi,lo) bf16 B-fragments, K padded 60->64 ----
        // Pairs with A columns (hi,lo,hi): dot = ahi*whi + alo*whi + ahi*wlo.
        int idx = (bid - PASSA_B - WCATE_B) * 256 + tid;   // exactly 4*2*8*64*8 = 32768
        int jj = idx & 7;
        int lane = (idx >> 3) & 63;
        int ntile = (idx >> 9) & 7;
        int kstep = (idx >> 12) & 1;
        int t = (idx >> 13) & 3;
        int ke = kstep * 32 + ((lane >> 4) * 8) + jj;
        int n = ntile * 16 + (lane & 15);
        float w = 0.f;
        int sel = 0;
        if (ke < 60) {
            int k0 = ke / 3;
            sel = ke - 3 * k0;
            w = W1[((size_t)t * IND + k0) * HD + n];
        }
        ushort16 hi = f2bf(w);
        W1e[idx] = (sel == 2) ? f2bf(w - bf2f1(hi)) : hi;
        return;
    }
    if (bid >= PASSA_B) {
        // ---- enc W2 (per type) -> bf16 B-fragment hi/lo ----
        int idx = (bid - PASSA_B) * 256 + tid;   // exactly 4*4*8*64*8 = 65536
        int jj = idx & 7;
        int lane = (idx >> 3) & 63;
        int ntile = (idx >> 9) & 7;
        int kt = (idx >> 12) & 3;
        int t = (idx >> 14) & 3;
        int k = kt * 32 + ((lane >> 4) * 8) + jj;
        int n = ntile * 16 + (lane & 15);
        float v = W2[((size_t)t * HD + k) * HD + n];
        ushort16 hi = f2bf(v);
        Weh[idx] = hi;
        Wel[idx] = f2bf(v - bf2f1(hi));
        return;
    }

    for (int k = tid; k < NBKT; k += 256) hist[k] = 0;
    __syncthreads();
    int e0 = bid * EDGES_PER_B, e1 = e0 + EDGES_PER_B;
    for (int e = e0 + tid; e < e1; e += 256) {
        int d = ei[NE + e];
        int s = ei[e];
        int r = et[e];
        int bkt = d >> 5;
        key16[e] = (ushort16)bkt;
        hdr32[e] = (unsigned)s | ((unsigned)r << 17) | ((unsigned)(d & 31) << 19);
        atomicAdd(&hist[bkt], 1);
    }
    __syncthreads();
    for (int k = tid; k < NBKT; k += 256) H[bid * NBKT + k] = hist[k];
}

// ---------------- scans: 2-phase H column-scan (round-11) + bucket scan ----------------
// Old k_s1: 13 blocks, each thread serially scans a 256-row column (5% of the
// device active). Split: s1a sums 32-row chunks (25000 threads, 98 blocks);
// s1b prefixes within each chunk from the chunk bases. 8x parallelism, serial
// chain 256 -> 32. Output values identical.

__global__ __launch_bounds__(256) void k_s1a(const int* __restrict__ H,
                                             int* __restrict__ csum) {
    int idx = blockIdx.x * 256 + threadIdx.x;   // idx = c*NBKT + bkt
    if (idx >= 8 * NBKT) return;
    int c = idx / NBKT;
    int bkt = idx - c * NBKT;
    const int* hp = H + (size_t)(c * 32) * NBKT + bkt;
    int s = 0;
#pragma unroll 8
    for (int r = 0; r < 32; r++) s += hp[(size_t)r * NBKT];
    csum[idx] = s;
}

__global__ __launch_bounds__(256) void k_s1b(int* __restrict__ H,
                                             const int* __restrict__ csum,
                                             int* __restrict__ btot) {
    int idx = blockIdx.x * 256 + threadIdx.x;   // idx = c*NBKT + bkt
    if (idx >= 8 * NBKT) return;
    int c = idx / NBKT;
    int bkt = idx - c * NBKT;
    int base = 0;
    for (int j = 0; j < c; j++) base += csum[j * NBKT + bkt];
    if (c == 7) btot[bkt] = base + csum[7 * NBKT + bkt];
    int* hp = H + (size_t)(c * 32) * NBKT + bkt;
    int run = base;
#pragma unroll 8
    for (int r = 0; r < 32; r++) {
        int t = hp[(size_t)r * NBKT];
        hp[(size_t)r * NBKT] = run;
        run += t;
    }
}

__global__ __launch_bounds__(1024) void k_s2(const int* __restrict__ btot,
                                             int* __restrict__ boff) {
    __shared__ int s[1024];
    int t = threadIdx.x;
    int v4[4];
    int sum = 0;
#pragma unroll
    for (int i = 0; i < 4; i++) {
        int idx = t * 4 + i;
        v4[i] = (idx < NBKT) ? btot[idx] : 0;
        sum += v4[i];
    }
    s[t] = sum;
    __syncthreads();
    for (int o = 1; o < 1024; o <<= 1) {
        int tv = (t >= o) ? s[t - o] : 0;
        __syncthreads();
        s[t] += tv;
        __syncthreads();
    }
    int run = s[t] - sum;
#pragma unroll
    for (int i = 0; i < 4; i++) {
        int idx = t * 4 + i;
        if (idx < NBKT) boff[idx] = run;
        run += v4[i];
    }
    if (t == 1023) boff[NBKT] = NE;
}

// ---------------- merged: single-window scatter | layer-W pack | encoder ----------------

__global__ __launch_bounds__(256) void k_fill2(
        const ushort16* __restrict__ key16, const unsigned* __restrict__ hdr32,
        const int* __restrict__ H, const int* __restrict__ boff,
        unsigned* __restrict__ packed,
        const unsigned* __restrict__ nodelist, const int* __restrict__ z,
        const float* __restrict__ sd, const float* __restrict__ df,
        const float* __restrict__ cond, const float* __restrict__ mult,
        const float* __restrict__ z_embed,
        const ushort16* __restrict__ W1e, const float* __restrict__ b1,
        const float* __restrict__ b2,
        unsigned char* __restrict__ xout,
        const float* __restrict__ rel_W, const float* __restrict__ lin_W,
        ushort16* __restrict__ Wbh, ushort16* __restrict__ Wbl,
        const ushort16* __restrict__ Weh, const ushort16* __restrict__ Wel) {
    __shared__ __attribute__((aligned(16))) char smem[13440];
    // union: fill cur[3125] int (12500 B) | enc Ae(4608)+h1b(8704)+ent(128)
    int bid = blockIdx.x;
    int tid = threadIdx.x;

    if (bid < FILL_B) {
        // ---- SINGLE-window atomic-free scatter (round-10: cur[3125]=12.5KB fits
        // the smem union; one edge pass instead of two -> halves key16/hdr32 reads) ----
        int* cur = (int*)smem;
        for (int k = tid; k < NBKT; k += 256)
            cur[k] = boff[k] + H[bid * NBKT + k];
        __syncthreads();
        int e0 = bid * EDGES_PER_B, e1 = e0 + EDGES_PER_B;
        for (int e = e0 + tid; e < e1; e += 256) {
            int kb = (int)key16[e];
            int p = atomicAdd(&cur[kb], 1);
            packed[p] = hdr32[e];
        }
        return;
    }
    int j = bid - FILL_B;
    if (j < WCAT_B) {
        // ---- layer weights -> bf16 B-fragment hi/lo (consumed by later dispatch) ----
        int idx = j * 256 + tid;           // exactly 2*512*128
        int jj = idx & 7;
        int lane = (idx >> 3) & 63;
        int ntile = (idx >> 9) & 7;
        int kt = (idx >> 12) & 15;
        int l = (idx >> 16) & 1;
        int k = kt * 32 + ((lane >> 4) * 8) + jj;
        int n = ntile * 16 + (lane & 15);
        float v;
        if (k < 384) v = rel_W[((l * 3 + (k >> 7)) * HD + (k & 127)) * HD + n];
        else         v = lin_W[(l * HD + (k - 384)) * HD + n];
        ushort16 hi = f2bf(v);
        Wbh[idx] = hi;
        Wbl[idx] = f2bf(v - bf2f1(hi));
        return;
    }
    j -= WCAT_B;
    if (j >= ENC_B) return;

    // ---- encoder: 32 same-type nodes; layer1 MFMA (tripled-K hi/lo) -> layer2 MFMA ----
    ushort16* Ae  = (ushort16*)smem;                     // [32][AES] bf16 expanded A
    ushort16* h1b = (ushort16*)(smem + 4608);            // [32][H1S] bf16
    unsigned* ent = (unsigned*)(smem + 4608 + 8704);

    int base = j * 32;
    if (tid < 32) ent[tid] = nodelist[base + tid];
    if (tid >= 64 && tid < 128) {   // zero A pad cols 60..63 (read by MFMA k=60..63)
        int r = (tid - 64) >> 1, c = 30 + (tid & 1);
        ((uint32*)Ae)[r * 36 + c] = 0;
    }
    __syncthreads();
    if (ent[0] == 0xFFFFFFFFu) return;
    int type = (int)(ent[0] >> 17);

    // A columns tripled per feature f: (hi, lo, hi) at cols 3f, 3f+1, 3f+2
    for (int idx = tid; idx < 32 * 20; idx += 256) {
        int nl = idx / 20, f = idx - nl * 20;
        unsigned e = ent[nl];
        float v = 0.f;
        if (e != 0xFFFFFFFFu) {
            int node = (int)(e & 0x1FFFF);
            if (f < 16)      v = z_embed[z[node] * 16 + f];
            else if (f == 16) v = sd[node];
            else if (f == 17) v = df[node];
            else if (f == 18) v = cond[node];
            else              v = mult[node];
        }
        ushort16 hi = f2bf(v);
        ushort16 lo = f2bf(v - bf2f1(hi));
        ushort16* ap = Ae + nl * AES + 3 * f;
        ap[0] = hi; ap[1] = lo; ap[2] = hi;
    }
    __syncthreads();

    int lane = tid & 63, wv = tid >> 6;
    int nt0 = 2 * wv, nt1 = 2 * wv + 1;
    int mrow0 = lane & 15, mrow1 = 16 + (lane & 15);
    int koff = (lane >> 4) * 8;

    // layer1: D[32x128] = Ae[32x64] @ W1e[type]  (single combined B; 8 MFMA/wave)
    {
        f32x4 e00 = {0.f, 0.f, 0.f, 0.f}, e01 = e00, e10 = e00, e11 = e00;
        const bf16x8* w1p = (const bf16x8*)(W1e + (size_t)type * 8192);
#pragma unroll
        for (int ks = 0; ks < 2; ks++) {
            bf16x8 af0 = *(const bf16x8*)&Ae[mrow0 * AES + ks * 32 + koff];
            bf16x8 af1 = *(const bf16x8*)&Ae[mrow1 * AES + ks * 32 + koff];
            bf16x8 bf0 = w1p[(ks * 8 + nt0) * 64 + lane];
            bf16x8 bf1 = w1p[(ks * 8 + nt1) * 64 + lane];
            e00 = __builtin_amdgcn_mfma_f32_16x16x32_bf16(af0, bf0, e00, 0, 0, 0);
            e01 = __builtin_amdgcn_mfma_f32_16x16x32_bf16(af0, bf1, e01, 0, 0, 0);
            e10 = __builtin_amdgcn_mfma_f32_16x16x32_bf16(af1, bf0, e10, 0, 0, 0);
            e11 = __builtin_amdgcn_mfma_f32_16x16x32_bf16(af1, bf1, e11, 0, 0, 0);
        }
        int c0 = nt0 * 16 + (lane & 15), c1 = nt1 * 16 + (lane & 15);
        float bb0 = b1[type * HD + c0], bb1 = b1[type * HD + c1];
        int rb2 = (lane >> 4) * 4;
#pragma unroll
        for (int r = 0; r < 4; r++) {
            h1b[(rb2 + r) * H1S + c0]      = f2bf(fmaxf(e00[r] + bb0, 0.f));
            h1b[(rb2 + r) * H1S + c1]      = f2bf(fmaxf(e01[r] + bb1, 0.f));
            h1b[(16 + rb2 + r) * H1S + c0] = f2bf(fmaxf(e10[r] + bb0, 0.f));
            h1b[(16 + rb2 + r) * H1S + c1] = f2bf(fmaxf(e11[r] + bb1, 0.f));
        }
    }
    __syncthreads();

    // layer2: D[32x128] = h1[32x128] @ W2[type] via MFMA hi/lo
    f32x4 a00 = {0.f, 0.f, 0.f, 0.f}, a01 = a00, a10 = a00, a11 = a00;
    const bf16x8* weh = (const bf16x8*)(Weh + (size_t)type * 16384);
    const bf16x8* wel = (const bf16x8*)(Wel + (size_t)type * 16384);
    const ushort16* h1p = h1b;
#pragma unroll
    for (int kt = 0; kt < 4; kt++) {
        bf16x8 af0 = *(const bf16x8*)&h1p[mrow0 * H1S + kt * 32 + koff];
        bf16x8 af1 = *(const bf16x8*)&h1p[mrow1 * H1S + kt * 32 + koff];
        bf16x8 bh0 = weh[(kt * 8 + nt0) * 64 + lane];
        bf16x8 bh1 = weh[(kt * 8 + nt1) * 64 + lane];
        bf16x8 bl0 = wel[(kt * 8 + nt0) * 64 + lane];
        bf16x8 bl1 = wel[(kt * 8 + nt1) * 64 + lane];
        a00 = __builtin_amdgcn_mfma_f32_16x16x32_bf16(af0, bh0, a00, 0, 0, 0);
        a01 = __builtin_amdgcn_mfma_f32_16x16x32_bf16(af0, bh1, a01, 0, 0, 0);
        a10 = __builtin_amdgcn_mfma_f32_16x16x32_bf16(af1, bh0, a10, 0, 0, 0);
        a11 = __builtin_amdgcn_mfma_f32_16x16x32_bf16(af1, bh1, a11, 0, 0, 0);
        a00 = __builtin_amdgcn_mfma_f32_16x16x32_bf16(af0, bl0, a00, 0, 0, 0);
        a01 = __builtin_amdgcn_mfma_f32_16x16x32_bf16(af0, bl1, a01, 0, 0, 0);
        a10 = __builtin_amdgcn_mfma_f32_16x16x32_bf16(af1, bl0, a10, 0, 0, 0);
        a11 = __builtin_amdgcn_mfma_f32_16x16x32_bf16(af1, bl1, a11, 0, 0, 0);
    }
    int c0 = nt0 * 16 + (lane & 15), c1 = nt1 * 16 + (lane & 15);
    float b20 = b2[type * HD + c0], b21 = b2[type * HD + c1];
    int rb = (lane >> 4) * 4;
#pragma unroll
    for (int r = 0; r < 4; r++) {
        int r0 = rb + r, r1 = 16 + rb + r;
        unsigned e0v = ent[r0], e1v = ent[r1];
        if (e0v != 0xFFFFFFFFu) {
            int node = (int)(e0v & 0x1FFFF);
            int p0 = __builtin_amdgcn_cvt_pk_fp8_f32(a00[r] + b20, a00[r] + b20, 0, false);
            int p1 = __builtin_amdgcn_cvt_pk_fp8_f32(a01[r] + b21, a01[r] + b21, 0, false);
            xout[(size_t)node * HD + c0] = (unsigned char)(p0 & 0xff);
            xout[(size_t)node * HD + c1] = (unsigned char)(p1 & 0xff);
        }
        if (e1v != 0xFFFFFFFFu) {
            int node = (int)(e1v & 0x1FFFF);
            int p0 = __builtin_amdgcn_cvt_pk_fp8_f32(a10[r] + b20, a10[r] + b20, 0, false);
            int p1 = __builtin_amdgcn_cvt_pk_fp8_f32(a11[r] + b21, a11[r] + b21, 0, false);
            xout[(size_t)node * HD + c0] = (unsigned char)(p0 & 0xff);
            xout[(size_t)node * HD + c1] = (unsigned char)(p1 & 0xff);
        }
    }
}

// ---------------- in-bucket counting sort: per-(dst,rel) segments padded to 8 ----------------
// Round-7: tid0's 96-iteration serial segp scan replaced by a 128-wide
// Hillis-Steele LDS scan (7 steps).

__global__ __launch_bounds__(256) void k_sort2(const unsigned* __restrict__ packed,
                                               const int* __restrict__ boff,
                                               unsigned* __restrict__ packed2,
                                               int* __restrict__ off,
                                               int* __restrict__ degarr) {
    __shared__ unsigned ebuf[SORT_CAP];
    __shared__ int hs[96];
    __shared__ int cur[96];
    __shared__ int segp[97];   // padded segment starts (96) + end
    __shared__ int scn[128];   // scan buffer
    int b = blockIdx.x;
    int tid = threadIdx.x;
    int base = boff[b];
    int tot = boff[b + 1] - base;
    if (tot > SORT_CAP) tot = SORT_CAP;   // statistically impossible (mean 512, sigma 23)
    int pb = base + PAD_PER_BKT * b;

    if (tid < 96) hs[tid] = 0;
    for (int e = tid; e < tot; e += 256) ebuf[e] = packed[base + e];
    __syncthreads();
    for (int e = tid; e < tot; e += 256) {
        unsigned h = ebuf[e];
        int key = (int)(h >> 19) * 3 + (int)((h >> 17) & 3);
        atomicAdd(&hs[key], 1);
    }
    __syncthreads();
    // parallel exclusive scan of padded segment sizes (128-wide Hillis-Steele)
    int padv = (tid < 96) ? ((hs[tid] + 7) & ~7) : 0;
    if (tid < 128) scn[tid] = padv;
    __syncthreads();
#pragma unroll
    for (int o = 1; o < 128; o <<= 1) {
        int tv = (tid < 128 && tid >= o) ? scn[tid - o] : 0;
        __syncthreads();
        if (tid < 128) scn[tid] += tv;
        __syncthreads();
    }
    if (tid < 96) segp[tid] = scn[tid] - padv;
    if (tid == 95) segp[96] = scn[95];
    __syncthreads();
    if (tid < 96) {
        cur[tid] = segp[tid];
        off[((b * 32 + tid / 3) << 2) + (tid % 3)] = pb + segp[tid];
    }
    if (tid >= 96 && tid < 128) {
        int n = tid - 96;
        off[((b * 32 + n) << 2) + 3] = pb + segp[3 * n + 3];
        degarr[b * 32 + n] = hs[3 * n] + hs[3 * n + 1] + hs[3 * n + 2];
    }
    __syncthreads();
    for (int e = tid; e < tot; e += 256) {
        unsigned h = ebuf[e];
        int key = (int)(h >> 19) * 3 + (int)((h >> 17) & 3);
        int p = atomicAdd(&cur[key], 1);
        packed2[pb + p] = h & 0x1FFFF;
    }
    __syncthreads();
    if (tid < 96) {   // sentinel-fill each segment's tail
        int e0 = segp[tid] + hs[tid];
        int e1 = segp[tid + 1];
        for (int q = e0; q < e1; q++) packed2[pb + q] = NN;
    }
}

// ---------------- fused layer: register agg (pure-rel 8-groups) -> MFMA -> LN ----------------
// 512 threads = 8 waves; wave w aggregates 4 nodes as TWO interleaved pairs
// (round-7: 4-chain SGPR 112 capped occupancy at 57%; 2-pair at SGPR 80 /
// occ 73% is the ILP x occupancy sweet spot). Every 8-group lies inside one
// rel segment (segments padded to 8 with zero-row sentinels) -> scalar 3-way
// branch picks the accumulator. Phase A is gather-latency/service-bound
// (x re-fetched ~7x across non-coherent XCD L2s; FETCH 93MB vs 12.8MB ideal).
// Epilogue: regW==nullptr -> fp8 x write; else fused mean-pool dot written as
// an UNCONTENDED per-block partial (G12 — 3125 same-address atomics cost ~11us).

#define LOADU8(U, Q)                                                          \
    U##0 = x[(int)Q##0 * 64 + lane]; U##1 = x[(int)Q##1 * 64 + lane];         \
    U##2 = x[(int)Q##2 * 64 + lane]; U##3 = x[(int)Q##3 * 64 + lane];         \
    U##4 = x[(int)Q##4 * 64 + lane]; U##5 = x[(int)Q##5 * 64 + lane];         \
    U##6 = x[(int)Q##6 * 64 + lane]; U##7 = x[(int)Q##7 * 64 + lane];

#define LOADQ8(Q, E)                                                          \
    Q##0 = packed[(E)];     Q##1 = packed[(E) + 1];                           \
    Q##2 = packed[(E) + 2]; Q##3 = packed[(E) + 3];                           \
    Q##4 = packed[(E) + 4]; Q##5 = packed[(E) + 5];                           \
    Q##6 = packed[(E) + 6]; Q##7 = packed[(E) + 7];

#define SUM8(S, U) {                                                          \
    f32x2 v0 = __builtin_amdgcn_cvt_pk_f32_fp8(U##0, false);                  \
    f32x2 v1 = __builtin_amdgcn_cvt_pk_f32_fp8(U##1, false);                  \
    f32x2 v2 = __builtin_amdgcn_cvt_pk_f32_fp8(U##2, false);                  \
    f32x2 v3 = __builtin_amdgcn_cvt_pk_f32_fp8(U##3, false);                  \
    f32x2 v4 = __builtin_amdgcn_cvt_pk_f32_fp8(U##4, false);                  \
    f32x2 v5 = __builtin_amdgcn_cvt_pk_f32_fp8(U##5, false);                  \
    f32x2 v6 = __builtin_amdgcn_cvt_pk_f32_fp8(U##6, false);                  \
    f32x2 v7 = __builtin_amdgcn_cvt_pk_f32_fp8(U##7, false);                  \
    S = ((v0 + v1) + (v2 + v3)) + ((v4 + v5) + (v6 + v7)); }

__global__ __launch_bounds__(512, 6) void k_fused(
        const ushort16* __restrict__ x,        // fp8 e4m3, 2 features per ushort, row stride 64
        const unsigned* __restrict__ packed,   // src-only, (dst,rel)-sorted, seg-8-padded
        const int* __restrict__ off, const int* __restrict__ degarr,
        const ushort16* __restrict__ Wbh, const ushort16* __restrict__ Wbl,
        const float* __restrict__ lb, const float* __restrict__ g,
        const float* __restrict__ bta, unsigned char* __restrict__ xout,
        const float* __restrict__ regW, float* __restrict__ partials) {
    __shared__ uint32 Alds[32 * ASTRIDE];   // bf16 A-tile [32][520]; aliased as hlds [32][132] f32
    __shared__ float stat[32][2];
    __shared__ float red[8];
    int tid = threadIdx.x;
    int lane = tid & 63;
    int wv = tid >> 6;                     // 0..7
    int nb = blockIdx.x * 32;

    int bv = off[((nb + wv * 4) << 2) + lane];        // 16 boundaries for 4 nodes
    int dgv = degarr[nb + wv * 4 + (lane & 3)];       // real degrees

    // ---- phase A: two interleaved node pairs ----
#pragma unroll
    for (int p = 0; p < 2; p++) {
        int nodeA = nb + wv * 4 + 2 * p;
        int nodeB = nodeA + 1;
        int bA0 = __builtin_amdgcn_readlane(bv, 8 * p + 0);
        int bA1 = __builtin_amdgcn_readlane(bv, 8 * p + 1);
        int bA2 = __builtin_amdgcn_readlane(bv, 8 * p + 2);
        int bA3 = __builtin_amdgcn_readlane(bv, 8 * p + 3);
        int bB0 = __builtin_amdgcn_readlane(bv, 8 * p + 4);
        int bB1 = __builtin_amdgcn_readlane(bv, 8 * p + 5);
        int bB2 = __builtin_amdgcn_readlane(bv, 8 * p + 6);
        int bB3 = __builtin_amdgcn_readlane(bv, 8 * p + 7);
        int dgA = __builtin_amdgcn_readlane(dgv, 2 * p);
        int dgB = __builtin_amdgcn_readlane(dgv, 2 * p + 1);
        float idA = 1.0f / (float)(dgA > 0 ? dgA : 1);
        float idB = 1.0f / (float)(dgB > 0 ? dgB : 1);
        int usA = x[nodeA * 64 + lane];               // self rows (early issue)
        int usB = x[nodeB * 64 + lane];
        f32x2 aA0 = {0.f, 0.f}, aA1 = aA0, aA2 = aA0;
        f32x2 aB0 = aA0, aB1 = aA0, aB2 = aA0;
        int eA = bA0, eB = bB0;
        unsigned qA0, qA1, qA2, qA3, qA4, qA5, qA6, qA7;
        unsigned qB0, qB1, qB2, qB3, qB4, qB5, qB6, qB7;
        if (eA < bA3) { LOADQ8(qA, eA) }
        if (eB < bB3) { LOADQ8(qB, eB) }
        while (true) {
            bool dA = eA < bA3, dB = eB < bB3;        // wave-uniform (SGPR bounds)
            if (!dA && !dB) break;
            int uA0, uA1, uA2, uA3, uA4, uA5, uA6, uA7;
            int uB0, uB1, uB2, uB3, uB4, uB5, uB6, uB7;
            if (dA) { LOADU8(uA, qA) }
            if (dB) { LOADU8(uB, qB) }
            // prefetch next 8 indices per active node (overread in slack;
            // values only register-copied, never dereferenced past loop exit)
            if (dA) { LOADQ8(qA, eA + 8) }
            if (dB) { LOADQ8(qB, eB + 8) }
            if (dA) {
                f32x2 s; SUM8(s, uA)
                if (eA < bA1)      aA0 += s;
                else if (eA < bA2) aA1 += s;
                else               aA2 += s;
                eA += 8;
            }
            if (dB) {
                f32x2 s; SUM8(s, uB)
                if (eB < bB1)      aB0 += s;
                else if (eB < bB2) aB1 += s;
                else               aB2 += s;
                eB += 8;
            }
        }
        uint32* arA = Alds + (wv * 4 + 2 * p) * ASTRIDE;
        uint32* arB = arA + ASTRIDE;
        f32x2 vsA = __builtin_amdgcn_cvt_pk_f32_fp8(usA, false);
        f32x2 vsB = __builtin_amdgcn_cvt_pk_f32_fp8(usB, false);
        arA[lane]       = pack2bf(make_float2(aA0.x * idA, aA0.y * idA));
        arA[64 + lane]  = pack2bf(make_float2(aA1.x * idA, aA1.y * idA));
        arA[128 + lane] = pack2bf(make_float2(aA2.x * idA, aA2.y * idA));
        arA[192 + lane] = pack2bf(make_float2(vsA.x, vsA.y));
        arB[lane]       = pack2bf(make_float2(aB0.x * idB, aB0.y * idB));
        arB[64 + lane]  = pack2bf(make_float2(aB1.x * idB, aB1.y * idB));
        arB[128 + lane] = pack2bf(make_float2(aB2.x * idB, aB2.y * idB));
        arB[192 + lane] = pack2bf(make_float2(vsB.x, vsB.y));
    }
    __syncthreads();

    // ---- phase B: MFMA GEMM (W = Whi + Wlo); wave w: n-tile w, m-tiles {0,1} ----
    f32x4 acc00 = {0.f, 0.f, 0.f, 0.f}, acc10 = acc00;
    int mrow0 = (lane & 15);
    int mrow1 = 16 + (lane & 15);
    int q4 = (lane >> 4) * 4;
    const bf16x8* wbh = (const bf16x8*)Wbh;
    const bf16x8* wbl = (const bf16x8*)Wbl;

#pragma unroll 4
    for (int kt = 0; kt < 16; kt++) {
        bf16x8 af0 = *(const bf16x8*)&Alds[mrow0 * ASTRIDE + kt * 16 + q4];
        bf16x8 af1 = *(const bf16x8*)&Alds[mrow1 * ASTRIDE + kt * 16 + q4];
        bf16x8 bh0 = wbh[(kt * 8 + wv) * 64 + lane];
        bf16x8 bl0 = wbl[(kt * 8 + wv) * 64 + lane];
        acc00 = __builtin_amdgcn_mfma_f32_16x16x32_bf16(af0, bh0, acc00, 0, 0, 0);
        acc10 = __builtin_amdgcn_mfma_f32_16x16x32_bf16(af1, bh0, acc10, 0, 0, 0);
        acc00 = __builtin_amdgcn_mfma_f32_16x16x32_bf16(af0, bl0, acc00, 0, 0, 0);
        acc10 = __builtin_amdgcn_mfma_f32_16x16x32_bf16(af1, bl0, acc10, 0, 0, 0);
    }
    __syncthreads();   // A-tile reads done; alias as hlds

    // ---- bias into LDS for LN stats ----
    float* hlds = (float*)Alds;            // [32][132]
    int n0 = wv * 16 + (lane & 15);
    float bj0 = lb[n0];
    int rbase = (lane >> 4) * 4;
#pragma unroll
    for (int r = 0; r < 4; r++) {
        hlds[(rbase + r) * 132 + n0]      = acc00[r] + bj0;
        hlds[(16 + rbase + r) * 132 + n0] = acc10[r] + bj0;
    }
    __syncthreads();

    {
        int node = tid >> 4, l16 = tid & 15;
        float s = 0.f, ss = 0.f;
#pragma unroll
        for (int i = 0; i < 8; i++) {
            float v = hlds[node * 132 + l16 + 16 * i];
            s += v; ss += v * v;
        }
        for (int d = 8; d >= 1; d >>= 1) {
            s += __shfl_down(s, d, 16);
            ss += __shfl_down(ss, d, 16);
        }
        if (l16 == 0) {
            float mu = s * (1.f / 128.f);
            float var = ss * (1.f / 128.f) - mu * mu;
            stat[node][0] = mu;
            stat[node][1] = rsqrtf(var + LNEPS);
        }
    }
    __syncthreads();

    // ---- LN epilogue: fp8 repack+store OR fused pool partial ----
    {
        int node = tid >> 4, q16 = tid & 15;
        float mu = stat[node][0], rs = stat[node][1];
        const float* hr = hlds + node * 132 + q16 * 8;
        float vv[8];
#pragma unroll
        for (int k = 0; k < 8; k++) {
            int f = q16 * 8 + k;
            vv[k] = (hr[k] - mu) * rs * g[f] + bta[f];
        }
        if (regW == nullptr) {
            int w[2];
#pragma unroll
            for (int p = 0; p < 2; p++) {
                int pk = __builtin_amdgcn_cvt_pk_fp8_f32(vv[p * 4 + 0], vv[p * 4 + 1], 0, false);
                pk = __builtin_amdgcn_cvt_pk_fp8_f32(vv[p * 4 + 2], vv[p * 4 + 3], pk, true);
                w[p] = pk;
            }
            *(int2*)(xout + (size_t)(nb + node) * 128 + q16 * 8) = make_int2(w[0], w[1]);
        } else {
            float s = 0.f;
#pragma unroll
            for (int k = 0; k < 8; k++) s += vv[k] * regW[q16 * 8 + k];
            for (int d = 32; d >= 1; d >>= 1) s += __shfl_down(s, d);
            if (lane == 0) red[wv] = s;
            __syncthreads();
            if (tid == 0) {
                partials[blockIdx.x] = red[0] + red[1] + red[2] + red[3] +
                                       red[4] + red[5] + red[6] + red[7];
            }
        }
    }
}

// ---------------- final reduction: 3125 partials -> scalar out ----------------

__global__ __launch_bounds__(1024) void k_red(const float* __restrict__ partials,
                                              const float* __restrict__ reg_b,
                                              float* __restrict__ out) {
    __shared__ float s[16];
    int tid = threadIdx.x;
    float v = 0.f;
    for (int i = tid; i < NBKT; i += 1024) v += partials[i];
    for (int d = 32; d >= 1; d >>= 1) v += __shfl_down(v, d);
    if ((tid & 63) == 0) s[tid >> 6] = v;
    __syncthreads();
    if (tid == 0) {
        float t = 0.f;
#pragma unroll
        for (int i = 0; i < 16; i++) t += s[i];
        out[0] = t * (1.0f / (float)NN) + reg_b[0];
    }
}

// ---------------- launcher ----------------

extern "C" void kernel_launch(void* const* d_in, const int* in_sizes, int n_in,
                              void* d_out, int out_size, void* d_ws, size_t ws_size,
                              hipStream_t stream) {
    const int*   z       = (const int*)d_in[0];
    const float* sd      = (const float*)d_in[1];
    const float* df      = (const float*)d_in[2];
    const float* cond    = (const float*)d_in[3];
    const float* mult    = (const float*)d_in[4];
    const int*   nt      = (const int*)d_in[5];
    const int*   ei      = (const int*)d_in[6];
    const int*   et      = (const int*)d_in[7];
    const float* z_embed = (const float*)d_in[8];
    const float* enc_W1  = (const float*)d_in[9];
    const float* enc_b1  = (const float*)d_in[10];
    const float* enc_W2  = (const float*)d_in[11];
    const float* enc_b2  = (const float*)d_in[12];
    const float* lin_W   = (const float*)d_in[13];
    const float* lin_b   = (const float*)d_in[14];
    const float* rel_W   = (const float*)d_in[15];
    const float* ln_g    = (const float*)d_in[16];
    const float* ln_b    = (const float*)d_in[17];
    const float* reg_W   = (const float*)d_in[18];
    const float* reg_b   = (const float*)d_in[19];
    float* out = (float*)d_out;

    char* p = (char*)d_ws;
    int* H          = (int*)p;      p += (size_t)PASSA_B * NBKT * 4;   // 3.2 MB
    int* btot       = (int*)p;      p += (size_t)4096 * 4;
    int* boff       = (int*)p;      p += (size_t)4096 * 4;
    int* csum       = (int*)p;      p += (size_t)8 * NBKT * 4;         // 100 KB (round-11)
    int* misc       = (int*)p;      p += 16 * 4;
    float* partials = (float*)p;    p += (size_t)4096 * 4;
    int* off        = (int*)p;      p += (size_t)400384 * 4;
    int* degarr     = (int*)p;      p += (size_t)100096 * 4;
    ushort16* key16 = (ushort16*)p; p += (size_t)NE * 2;
    unsigned* hdr32 = (unsigned*)p; p += (size_t)NE * 4;
    unsigned* packed   = (unsigned*)p; p += (size_t)NE * 4;
    unsigned* packed2  = (unsigned*)p; p += (size_t)(NEP + 16) * 4;   // +16 dword prefetch slack
    unsigned* nodelist = (unsigned*)p; p += (size_t)NLIST2 * 4;
    ushort16* Wbh   = (ushort16*)p; p += (size_t)2 * 512 * 128 * 2;
    ushort16* Wbl   = (ushort16*)p; p += (size_t)2 * 512 * 128 * 2;
    ushort16* Weh   = (ushort16*)p; p += (size_t)65536 * 2;
    ushort16* Wel   = (ushort16*)p; p += (size_t)65536 * 2;
    ushort16* W1e   = (ushort16*)p; p += (size_t)32768 * 2;
    unsigned char* x0 = (unsigned char*)p; p += (size_t)(NN + 1) * HD;
    unsigned char* x1 = (unsigned char*)p; p += (size_t)(NN + 1) * HD;

    hipMemsetAsync(misc, 0, 64, stream);
    hipMemsetAsync(nodelist, 0xFF, (size_t)NLIST2 * 4, stream);

    k_hist<<<PASSA_B + WCATE_B + W1P_B + FILLN_B, 256, 0, stream>>>(
        ei, et, H, key16, hdr32, enc_W2, Weh, Wel, enc_W1, W1e,
        nt, misc, nodelist, (uint32*)x0, (uint32*)x1);
    k_s1a<<<(8 * NBKT + 255) / 256, 256, 0, stream>>>(H, csum);
    k_s1b<<<(8 * NBKT + 255) / 256, 256, 0, stream>>>(H, csum, btot);
    k_s2<<<1, 1024, 0, stream>>>(btot, boff);
    k_fill2<<<FILL_B + WCAT_B + ENC_B, 256, 0, stream>>>(
        key16, hdr32, H, boff, packed,
        nodelist, z, sd, df, cond, mult, z_embed,
        W1e, enc_b1, enc_b2, x0,
        rel_W, lin_W, Wbh, Wbl, Weh, Wel);
    k_sort2<<<NBKT, 256, 0, stream>>>(packed, boff, packed2, off, degarr);

    // layer 0: x0 -> x1 (fp8 write)
    k_fused<<<NBKT, 512, 0, stream>>>((const ushort16*)x0, packed2, off, degarr,
                                      Wbh, Wbl,
                                      lin_b, ln_g, ln_b,
                                      x1, nullptr, partials);
    // layer 1: x1 -> per-block pool partials (x write skipped)
    k_fused<<<NBKT, 512, 0, stream>>>((const ushort16*)x1, packed2, off, degarr,
                                      Wbh + (size_t)512 * 128, Wbl + (size_t)512 * 128,
                                      lin_b + HD, ln_g + HD, ln_b + HD,
                                      x0, reg_W, partials);
    k_red<<<1, 1024, 0, stream>>>(partials, reg_b, out);
}

// Round 13
// 340.006 us; speedup vs baseline: 1.0220x; 1.0220x over previous
//
#include <hip/hip_runtime.h>

#define NN 100000
#define NE 1600000
#define HD 128
#define IND 20
#define LNEPS 1e-5f
#define NLIST2 400000   // 4 type regions of NN
#define NBKT 3125       // dst>>5 buckets == k_fused blocks
#define PASSA_B 256     // FILL_B==PASSA_B sets scatter parallelism (round-10 lesson)
#define EDGES_PER_B 6250
#define FILL_B 256
#define WCAT_B 512
#define WCATE_B 256
#define W1P_B 128       // enc-W1 expanded-K pack role blocks
#define FILLN_B 400
#define ENC_B 12500
#define ASTRIDE 260     // A-tile row stride in 32-bit words (520 bf16)
#define SORT_CAP 4096
#define PAD_PER_BKT 672 // 96 segments * up to 7 pad each (seg pad-to-8)
#define NEP (NE + NBKT * PAD_PER_BKT)
#define H1S 136         // enc h1 row stride in bf16 (272 B, 16B-aligned rows)
#define AES 72          // enc expanded-A row stride in bf16 (144 B, 16B-aligned rows)

typedef unsigned int uint32;
typedef unsigned short ushort16;
typedef __attribute__((ext_vector_type(8))) short bf16x8;
typedef __attribute__((ext_vector_type(4))) float f32x4;
typedef __attribute__((ext_vector_type(2))) float f32x2;

__device__ __forceinline__ ushort16 f2bf(float f) {
    uint32 u = __float_as_uint(f);
    u += 0x7fffu + ((u >> 16) & 1u);   // round-to-nearest-even
    return (ushort16)(u >> 16);
}
__device__ __forceinline__ float bf2f1(ushort16 h) {
    return __uint_as_float(((uint32)h) << 16);
}
__device__ __forceinline__ uint32 pack2bf(float2 v) {
    return (uint32)f2bf(v.x) | ((uint32)f2bf(v.y) << 16);
}

// ---------------- pass A: bucket histogram | enc-W2 pack | enc-W1 pack | node list ----------
// Node-list role uses BLOCK-BATCHED atomics (round-5 fix: 4 parallel atomics
// per block instead of 6400 serial wave-leader atomics; was 87us idle-wait).

__global__ __launch_bounds__(256) void k_hist(const int* __restrict__ ei,
                                              const int* __restrict__ et,
                                              int* __restrict__ H,
                                              ushort16* __restrict__ key16,
                                              unsigned* __restrict__ hdr32,
                                              const float* __restrict__ W2,
                                              ushort16* __restrict__ Weh,
                                              ushort16* __restrict__ Wel,
                                              const float* __restrict__ W1,
                                              ushort16* __restrict__ W1e,
                                              const int* __restrict__ nt,
                                              int* misc, unsigned* nodelist,
                                              uint32* x0, uint32* x1) {
    __shared__ int hist[NBKT];
    __shared__ int cnt4[4][4];   // [wave][type] node-list role
    __shared__ int base4[4];     // block base per type
    int bid = blockIdx.x, tid = threadIdx.x;

    if (bid >= PASSA_B + WCATE_B + W1P_B) {
        // ---- node list (block-batched atomics) + zero sentinel rows ----
        int rb = bid - PASSA_B - WCATE_B - W1P_B;
        int lane = tid & 63;
        int w = tid >> 6;
        if (rb == 0 && tid < 32) {     // zero row NN of both x buffers
            x0[(size_t)NN * 32 + tid] = 0;
            x1[(size_t)NN * 32 + tid] = 0;
        }
        int i = rb * 256 + tid;        // 400*256 = 102400 >= NN: single step
        int t = (i < NN) ? nt[i] : -1;
        unsigned long long lt = ((unsigned long long)1 << lane) - 1;
        int pre[4], wc[4];
#pragma unroll
        for (int tt = 0; tt < 4; tt++) {
            unsigned long long m = __ballot(t == tt);
            pre[tt] = (int)__popcll(m & lt);
            wc[tt] = (int)__popcll(m);
        }
        if (lane == 0) {
            cnt4[w][0] = wc[0]; cnt4[w][1] = wc[1];
            cnt4[w][2] = wc[2]; cnt4[w][3] = wc[3];
        }
        __syncthreads();
        if (tid < 4) {   // 4 PARALLEL atomics per block (one per type)
            int tot = cnt4[0][tid] + cnt4[1][tid] + cnt4[2][tid] + cnt4[3][tid];
            base4[tid] = tot ? atomicAdd(&misc[8 + tid], tot) : 0;
        }
        __syncthreads();
        if (t >= 0) {
            int off = base4[t] + pre[t];
#pragma unroll
            for (int wp = 0; wp < 3; wp++) if (wp < w) off += cnt4[wp][t];
            nodelist[t * NN + off] = (unsigned)i | ((unsigned)t << 17);
        }
        return;
    }
    if (bid >= PASSA_B + WCATE_B) {
        // ---- enc W1 -> tripled-K (hi,hi,lo) bf16 B-fragments, K padded 60->64 ----
        // Pairs with A columns (hi,lo,hi): dot = ahi*whi + alo*whi + ahi*wlo.
        int idx = (bid - PASSA_B - WCATE_B) * 256 + tid;   // exactly 4*2*8*64*8 = 32768
        int jj = idx & 7;
        int lane = (idx >> 3) & 63;
        int ntile = (idx >> 9) & 7;
        int kstep = (idx >> 12) & 1;
        int t = (idx >> 13) & 3;
        int ke = kstep * 32 + ((lane >> 4) * 8) + jj;
        int n = ntile * 16 + (lane & 15);
        float w = 0.f;
        int sel = 0;
        if (ke < 60) {
            int k0 = ke / 3;
            sel = ke - 3 * k0;
            w = W1[((size_t)t * IND + k0) * HD + n];
        }
        ushort16 hi = f2bf(w);
        W1e[idx] = (sel == 2) ? f2bf(w - bf2f1(hi)) : hi;
        return;
    }
    if (bid >= PASSA_B) {
        // ---- enc W2 (per type) -> bf16 B-fragment hi/lo ----
        int idx = (bid - PASSA_B) * 256 + tid;   // exactly 4*4*8*64*8 = 65536
        int jj = idx & 7;
        int lane = (idx >> 3) & 63;
        int ntile = (idx >> 9) & 7;
        int kt = (idx >> 12) & 3;
        int t = (idx >> 14) & 3;
        int k = kt * 32 + ((lane >> 4) * 8) + jj;
        int n = ntile * 16 + (lane & 15);
        float v = W2[((size_t)t * HD + k) * HD + n];
        ushort16 hi = f2bf(v);
        Weh[idx] = hi;
        Wel[idx] = f2bf(v - bf2f1(hi));
        return;
    }

    for (int k = tid; k < NBKT; k += 256) hist[k] = 0;
    __syncthreads();
    int e0 = bid * EDGES_PER_B, e1 = e0 + EDGES_PER_B;
    for (int e = e0 + tid; e < e1; e += 256) {
        int d = ei[NE + e];
        int s = ei[e];
        int r = et[e];
        int bkt = d >> 5;
        key16[e] = (ushort16)bkt;
        hdr32[e] = (unsigned)s | ((unsigned)r << 17) | ((unsigned)(d & 31) << 19);
        atomicAdd(&hist[bkt], 1);
    }
    __syncthreads();
    for (int k = tid; k < NBKT; k += 256) H[bid * NBKT + k] = hist[k];
}

// ---------------- scans: H column-scan + bucket scan ----------------
// (round-12: reverted round-11's 2-phase split — measured +7us net; the
// serial 256-row column scan was never a significant cost.)

__global__ __launch_bounds__(256) void k_s1(int* __restrict__ H, int* __restrict__ btot) {
    int bkt = blockIdx.x * 256 + threadIdx.x;
    if (bkt >= NBKT) return;
    int run = 0;
    for (int jm = 0; jm < PASSA_B; jm += 8) {
        int t0 = H[(jm + 0) * NBKT + bkt];
        int t1 = H[(jm + 1) * NBKT + bkt];
        int t2 = H[(jm + 2) * NBKT + bkt];
        int t3 = H[(jm + 3) * NBKT + bkt];
        int t4 = H[(jm + 4) * NBKT + bkt];
        int t5 = H[(jm + 5) * NBKT + bkt];
        int t6 = H[(jm + 6) * NBKT + bkt];
        int t7 = H[(jm + 7) * NBKT + bkt];
        H[(jm + 0) * NBKT + bkt] = run; run += t0;
        H[(jm + 1) * NBKT + bkt] = run; run += t1;
        H[(jm + 2) * NBKT + bkt] = run; run += t2;
        H[(jm + 3) * NBKT + bkt] = run; run += t3;
        H[(jm + 4) * NBKT + bkt] = run; run += t4;
        H[(jm + 5) * NBKT + bkt] = run; run += t5;
        H[(jm + 6) * NBKT + bkt] = run; run += t6;
        H[(jm + 7) * NBKT + bkt] = run; run += t7;
    }
    btot[bkt] = run;
}

__global__ __launch_bounds__(1024) void k_s2(const int* __restrict__ btot,
                                             int* __restrict__ boff) {
    __shared__ int s[1024];
    int t = threadIdx.x;
    int v4[4];
    int sum = 0;
#pragma unroll
    for (int i = 0; i < 4; i++) {
        int idx = t * 4 + i;
        v4[i] = (idx < NBKT) ? btot[idx] : 0;
        sum += v4[i];
    }
    s[t] = sum;
    __syncthreads();
    for (int o = 1; o < 1024; o <<= 1) {
        int tv = (t >= o) ? s[t - o] : 0;
        __syncthreads();
        s[t] += tv;
        __syncthreads();
    }
    int run = s[t] - sum;
#pragma unroll
    for (int i = 0; i < 4; i++) {
        int idx = t * 4 + i;
        if (idx < NBKT) boff[idx] = run;
        run += v4[i];
    }
    if (t == 1023) boff[NBKT] = NE;
}

// ---------------- merged: single-window scatter | layer-W pack | encoder ----------------

__global__ __launch_bounds__(256) void k_fill2(
        const ushort16* __restrict__ key16, const unsigned* __restrict__ hdr32,
        const int* __restrict__ H, const int* __restrict__ boff,
        unsigned* __restrict__ packed,
        const unsigned* __restrict__ nodelist, const int* __restrict__ z,
        const float* __restrict__ sd, const float* __restrict__ df,
        const float* __restrict__ cond, const float* __restrict__ mult,
        const float* __restrict__ z_embed,
        const ushort16* __restrict__ W1e, const float* __restrict__ b1,
        const float* __restrict__ b2,
        unsigned char* __restrict__ xout,
        const float* __restrict__ rel_W, const float* __restrict__ lin_W,
        ushort16* __restrict__ Wbh, ushort16* __restrict__ Wbl,
        const ushort16* __restrict__ Weh, const ushort16* __restrict__ Wel) {
    __shared__ __attribute__((aligned(16))) char smem[13440];
    // union: fill cur[3125] int (12500 B) | enc Ae(4608)+h1b(8704)+ent(128)
    int bid = blockIdx.x;
    int tid = threadIdx.x;

    if (bid < FILL_B) {
        // ---- SINGLE-window atomic-free scatter (round-10: cur[3125]=12.5KB fits
        // the smem union; one edge pass instead of two -> halves key16/hdr32 reads) ----
        int* cur = (int*)smem;
        for (int k = tid; k < NBKT; k += 256)
            cur[k] = boff[k] + H[bid * NBKT + k];
        __syncthreads();
        int e0 = bid * EDGES_PER_B, e1 = e0 + EDGES_PER_B;
        for (int e = e0 + tid; e < e1; e += 256) {
            int kb = (int)key16[e];
            int p = atomicAdd(&cur[kb], 1);
            packed[p] = hdr32[e];
        }
        return;
    }
    int j = bid - FILL_B;
    if (j < WCAT_B) {
        // ---- layer weights -> bf16 B-fragment hi/lo (consumed by later dispatch) ----
        int idx = j * 256 + tid;           // exactly 2*512*128
        int jj = idx & 7;
        int lane = (idx >> 3) & 63;
        int ntile = (idx >> 9) & 7;
        int kt = (idx >> 12) & 15;
        int l = (idx >> 16) & 1;
        int k = kt * 32 + ((lane >> 4) * 8) + jj;
        int n = ntile * 16 + (lane & 15);
        float v;
        if (k < 384) v = rel_W[((l * 3 + (k >> 7)) * HD + (k & 127)) * HD + n];
        else         v = lin_W[(l * HD + (k - 384)) * HD + n];
        ushort16 hi = f2bf(v);
        Wbh[idx] = hi;
        Wbl[idx] = f2bf(v - bf2f1(hi));
        return;
    }
    j -= WCAT_B;
    if (j >= ENC_B) return;

    // ---- encoder: 32 same-type nodes; layer1 MFMA (tripled-K hi/lo) -> layer2 MFMA ----
    ushort16* Ae  = (ushort16*)smem;                     // [32][AES] bf16 expanded A
    ushort16* h1b = (ushort16*)(smem + 4608);            // [32][H1S] bf16
    unsigned* ent = (unsigned*)(smem + 4608 + 8704);

    int base = j * 32;
    if (tid < 32) ent[tid] = nodelist[base + tid];
    if (tid >= 64 && tid < 128) {   // zero A pad cols 60..63 (read by MFMA k=60..63)
        int r = (tid - 64) >> 1, c = 30 + (tid & 1);
        ((uint32*)Ae)[r * 36 + c] = 0;
    }
    __syncthreads();
    if (ent[0] == 0xFFFFFFFFu) return;
    int type = (int)(ent[0] >> 17);

    // A columns tripled per feature f: (hi, lo, hi) at cols 3f, 3f+1, 3f+2
    for (int idx = tid; idx < 32 * 20; idx += 256) {
        int nl = idx / 20, f = idx - nl * 20;
        unsigned e = ent[nl];
        float v = 0.f;
        if (e != 0xFFFFFFFFu) {
            int node = (int)(e & 0x1FFFF);
            if (f < 16)      v = z_embed[z[node] * 16 + f];
            else if (f == 16) v = sd[node];
            else if (f == 17) v = df[node];
            else if (f == 18) v = cond[node];
            else              v = mult[node];
        }
        ushort16 hi = f2bf(v);
        ushort16 lo = f2bf(v - bf2f1(hi));
        ushort16* ap = Ae + nl * AES + 3 * f;
        ap[0] = hi; ap[1] = lo; ap[2] = hi;
    }
    __syncthreads();

    int lane = tid & 63, wv = tid >> 6;
    int nt0 = 2 * wv, nt1 = 2 * wv + 1;
    int mrow0 = lane & 15, mrow1 = 16 + (lane & 15);
    int koff = (lane >> 4) * 8;

    // layer1: D[32x128] = Ae[32x64] @ W1e[type]  (single combined B; 8 MFMA/wave)
    {
        f32x4 e00 = {0.f, 0.f, 0.f, 0.f}, e01 = e00, e10 = e00, e11 = e00;
        const bf16x8* w1p = (const bf16x8*)(W1e + (size_t)type * 8192);
#pragma unroll
        for (int ks = 0; ks < 2; ks++) {
            bf16x8 af0 = *(const bf16x8*)&Ae[mrow0 * AES + ks * 32 + koff];
            bf16x8 af1 = *(const bf16x8*)&Ae[mrow1 * AES + ks * 32 + koff];
            bf16x8 bf0 = w1p[(ks * 8 + nt0) * 64 + lane];
            bf16x8 bf1 = w1p[(ks * 8 + nt1) * 64 + lane];
            e00 = __builtin_amdgcn_mfma_f32_16x16x32_bf16(af0, bf0, e00, 0, 0, 0);
            e01 = __builtin_amdgcn_mfma_f32_16x16x32_bf16(af0, bf1, e01, 0, 0, 0);
            e10 = __builtin_amdgcn_mfma_f32_16x16x32_bf16(af1, bf0, e10, 0, 0, 0);
            e11 = __builtin_amdgcn_mfma_f32_16x16x32_bf16(af1, bf1, e11, 0, 0, 0);
        }
        int c0 = nt0 * 16 + (lane & 15), c1 = nt1 * 16 + (lane & 15);
        float bb0 = b1[type * HD + c0], bb1 = b1[type * HD + c1];
        int rb2 = (lane >> 4) * 4;
#pragma unroll
        for (int r = 0; r < 4; r++) {
            h1b[(rb2 + r) * H1S + c0]      = f2bf(fmaxf(e00[r] + bb0, 0.f));
            h1b[(rb2 + r) * H1S + c1]      = f2bf(fmaxf(e01[r] + bb1, 0.f));
            h1b[(16 + rb2 + r) * H1S + c0] = f2bf(fmaxf(e10[r] + bb0, 0.f));
            h1b[(16 + rb2 + r) * H1S + c1] = f2bf(fmaxf(e11[r] + bb1, 0.f));
        }
    }
    __syncthreads();

    // layer2: D[32x128] = h1[32x128] @ W2[type] via MFMA hi/lo
    f32x4 a00 = {0.f, 0.f, 0.f, 0.f}, a01 = a00, a10 = a00, a11 = a00;
    const bf16x8* weh = (const bf16x8*)(Weh + (size_t)type * 16384);
    const bf16x8* wel = (const bf16x8*)(Wel + (size_t)type * 16384);
    const ushort16* h1p = h1b;
#pragma unroll
    for (int kt = 0; kt < 4; kt++) {
        bf16x8 af0 = *(const bf16x8*)&h1p[mrow0 * H1S + kt * 32 + koff];
        bf16x8 af1 = *(const bf16x8*)&h1p[mrow1 * H1S + kt * 32 + koff];
        bf16x8 bh0 = weh[(kt * 8 + nt0) * 64 + lane];
        bf16x8 bh1 = weh[(kt * 8 + nt1) * 64 + lane];
        bf16x8 bl0 = wel[(kt * 8 + nt0) * 64 + lane];
        bf16x8 bl1 = wel[(kt * 8 + nt1) * 64 + lane];
        a00 = __builtin_amdgcn_mfma_f32_16x16x32_bf16(af0, bh0, a00, 0, 0, 0);
        a01 = __builtin_amdgcn_mfma_f32_16x16x32_bf16(af0, bh1, a01, 0, 0, 0);
        a10 = __builtin_amdgcn_mfma_f32_16x16x32_bf16(af1, bh0, a10, 0, 0, 0);
        a11 = __builtin_amdgcn_mfma_f32_16x16x32_bf16(af1, bh1, a11, 0, 0, 0);
        a00 = __builtin_amdgcn_mfma_f32_16x16x32_bf16(af0, bl0, a00, 0, 0, 0);
        a01 = __builtin_amdgcn_mfma_f32_16x16x32_bf16(af0, bl1, a01, 0, 0, 0);
        a10 = __builtin_amdgcn_mfma_f32_16x16x32_bf16(af1, bl0, a10, 0, 0, 0);
        a11 = __builtin_amdgcn_mfma_f32_16x16x32_bf16(af1, bl1, a11, 0, 0, 0);
    }
    int c0 = nt0 * 16 + (lane & 15), c1 = nt1 * 16 + (lane & 15);
    float b20 = b2[type * HD + c0], b21 = b2[type * HD + c1];
    int rb = (lane >> 4) * 4;
#pragma unroll
    for (int r = 0; r < 4; r++) {
        int r0 = rb + r, r1 = 16 + rb + r;
        unsigned e0v = ent[r0], e1v = ent[r1];
        if (e0v != 0xFFFFFFFFu) {
            int node = (int)(e0v & 0x1FFFF);
            int p0 = __builtin_amdgcn_cvt_pk_fp8_f32(a00[r] + b20, a00[r] + b20, 0, false);
            int p1 = __builtin_amdgcn_cvt_pk_fp8_f32(a01[r] + b21, a01[r] + b21, 0, false);
            xout[(size_t)node * HD + c0] = (unsigned char)(p0 & 0xff);
            xout[(size_t)node * HD + c1] = (unsigned char)(p1 & 0xff);
        }
        if (e1v != 0xFFFFFFFFu) {
            int node = (int)(e1v & 0x1FFFF);
            int p0 = __builtin_amdgcn_cvt_pk_fp8_f32(a10[r] + b20, a10[r] + b20, 0, false);
            int p1 = __builtin_amdgcn_cvt_pk_fp8_f32(a11[r] + b21, a11[r] + b21, 0, false);
            xout[(size_t)node * HD + c0] = (unsigned char)(p0 & 0xff);
            xout[(size_t)node * HD + c1] = (unsigned char)(p1 & 0xff);
        }
    }
}

// ---------------- in-bucket counting sort: per-(dst,rel) segments padded to 8 ----------------
// Round-7: tid0's 96-iteration serial segp scan replaced by a 128-wide
// Hillis-Steele LDS scan (7 steps).

__global__ __launch_bounds__(256) void k_sort2(const unsigned* __restrict__ packed,
                                               const int* __restrict__ boff,
                                               unsigned* __restrict__ packed2,
                                               int* __restrict__ off,
                                               int* __restrict__ degarr) {
    __shared__ unsigned ebuf[SORT_CAP];
    __shared__ int hs[96];
    __shared__ int cur[96];
    __shared__ int segp[97];   // padded segment starts (96) + end
    __shared__ int scn[128];   // scan buffer
    int b = blockIdx.x;
    int tid = threadIdx.x;
    int base = boff[b];
    int tot = boff[b + 1] - base;
    if (tot > SORT_CAP) tot = SORT_CAP;   // statistically impossible (mean 512, sigma 23)
    int pb = base + PAD_PER_BKT * b;

    if (tid < 96) hs[tid] = 0;
    for (int e = tid; e < tot; e += 256) ebuf[e] = packed[base + e];
    __syncthreads();
    for (int e = tid; e < tot; e += 256) {
        unsigned h = ebuf[e];
        int key = (int)(h >> 19) * 3 + (int)((h >> 17) & 3);
        atomicAdd(&hs[key], 1);
    }
    __syncthreads();
    // parallel exclusive scan of padded segment sizes (128-wide Hillis-Steele)
    int padv = (tid < 96) ? ((hs[tid] + 7) & ~7) : 0;
    if (tid < 128) scn[tid] = padv;
    __syncthreads();
#pragma unroll
    for (int o = 1; o < 128; o <<= 1) {
        int tv = (tid < 128 && tid >= o) ? scn[tid - o] : 0;
        __syncthreads();
        if (tid < 128) scn[tid] += tv;
        __syncthreads();
    }
    if (tid < 96) segp[tid] = scn[tid] - padv;
    if (tid == 95) segp[96] = scn[95];
    __syncthreads();
    if (tid < 96) {
        cur[tid] = segp[tid];
        off[((b * 32 + tid / 3) << 2) + (tid % 3)] = pb + segp[tid];
    }
    if (tid >= 96 && tid < 128) {
        int n = tid - 96;
        off[((b * 32 + n) << 2) + 3] = pb + segp[3 * n + 3];
        degarr[b * 32 + n] = hs[3 * n] + hs[3 * n + 1] + hs[3 * n + 2];
    }
    __syncthreads();
    for (int e = tid; e < tot; e += 256) {
        unsigned h = ebuf[e];
        int key = (int)(h >> 19) * 3 + (int)((h >> 17) & 3);
        int p = atomicAdd(&cur[key], 1);
        packed2[pb + p] = h & 0x1FFFF;
    }
    __syncthreads();
    if (tid < 96) {   // sentinel-fill each segment's tail
        int e0 = segp[tid] + hs[tid];
        int e1 = segp[tid + 1];
        for (int q = e0; q < e1; q++) packed2[pb + q] = NN;
    }
}

// ---------------- fused layer: register agg (pure-rel 8-groups) -> MFMA -> LN ----------------
// 512 threads = 8 waves; wave w aggregates 4 nodes as TWO interleaved pairs
// (round-7: 4-chain SGPR 112 capped occupancy at 57%; 2-pair at SGPR 80 /
// occ 73% is the ILP x occupancy sweet spot). Every 8-group lies inside one
// rel segment (segments padded to 8 with zero-row sentinels) -> scalar 3-way
// branch picks the accumulator. Phase A is gather request-latency-bound
// (round-12: FETCH 93->165MB with ~2% time change — NOT BW-bound; random
// row gather across non-coherent XCD L2s).
// Epilogue: regW==nullptr -> fp8 x write; else fused mean-pool dot written as
// an UNCONTENDED per-block partial (G12 — 3125 same-address atomics cost ~11us).

#define LOADU8(U, Q)                                                          \
    U##0 = x[(int)Q##0 * 64 + lane]; U##1 = x[(int)Q##1 * 64 + lane];         \
    U##2 = x[(int)Q##2 * 64 + lane]; U##3 = x[(int)Q##3 * 64 + lane];         \
    U##4 = x[(int)Q##4 * 64 + lane]; U##5 = x[(int)Q##5 * 64 + lane];         \
    U##6 = x[(int)Q##6 * 64 + lane]; U##7 = x[(int)Q##7 * 64 + lane];

#define LOADQ8(Q, E)                                                          \
    Q##0 = packed[(E)];     Q##1 = packed[(E) + 1];                           \
    Q##2 = packed[(E) + 2]; Q##3 = packed[(E) + 3];                           \
    Q##4 = packed[(E) + 4]; Q##5 = packed[(E) + 5];                           \
    Q##6 = packed[(E) + 6]; Q##7 = packed[(E) + 7];

#define SUM8(S, U) {                                                          \
    f32x2 v0 = __builtin_amdgcn_cvt_pk_f32_fp8(U##0, false);                  \
    f32x2 v1 = __builtin_amdgcn_cvt_pk_f32_fp8(U##1, false);                  \
    f32x2 v2 = __builtin_amdgcn_cvt_pk_f32_fp8(U##2, false);                  \
    f32x2 v3 = __builtin_amdgcn_cvt_pk_f32_fp8(U##3, false);                  \
    f32x2 v4 = __builtin_amdgcn_cvt_pk_f32_fp8(U##4, false);                  \
    f32x2 v5 = __builtin_amdgcn_cvt_pk_f32_fp8(U##5, false);                  \
    f32x2 v6 = __builtin_amdgcn_cvt_pk_f32_fp8(U##6, false);                  \
    f32x2 v7 = __builtin_amdgcn_cvt_pk_f32_fp8(U##7, false);                  \
    S = ((v0 + v1) + (v2 + v3)) + ((v4 + v5) + (v6 + v7)); }

__global__ __launch_bounds__(512, 6) void k_fused(
        const ushort16* __restrict__ x,        // fp8 e4m3, 2 features per ushort, row stride 64
        const unsigned* __restrict__ packed,   // src-only, (dst,rel)-sorted, seg-8-padded
        const int* __restrict__ off, const int* __restrict__ degarr,
        const ushort16* __restrict__ Wbh, const ushort16* __restrict__ Wbl,
        const float* __restrict__ lb, const float* __restrict__ g,
        const float* __restrict__ bta, unsigned char* __restrict__ xout,
        const float* __restrict__ regW, float* __restrict__ partials) {
    __shared__ uint32 Alds[32 * ASTRIDE];   // bf16 A-tile [32][520]; aliased as hlds [32][132] f32
    __shared__ float stat[32][2];
    __shared__ float red[8];
    int tid = threadIdx.x;
    int lane = tid & 63;
    int wv = tid >> 6;                     // 0..7
    int nb = blockIdx.x * 32;

    int bv = off[((nb + wv * 4) << 2) + lane];        // 16 boundaries for 4 nodes
    int dgv = degarr[nb + wv * 4 + (lane & 3)];       // real degrees

    // ---- phase A: two interleaved node pairs ----
#pragma unroll
    for (int p = 0; p < 2; p++) {
        int nodeA = nb + wv * 4 + 2 * p;
        int nodeB = nodeA + 1;
        int bA0 = __builtin_amdgcn_readlane(bv, 8 * p + 0);
        int bA1 = __builtin_amdgcn_readlane(bv, 8 * p + 1);
        int bA2 = __builtin_amdgcn_readlane(bv, 8 * p + 2);
        int bA3 = __builtin_amdgcn_readlane(bv, 8 * p + 3);
        int bB0 = __builtin_amdgcn_readlane(bv, 8 * p + 4);
        int bB1 = __builtin_amdgcn_readlane(bv, 8 * p + 5);
        int bB2 = __builtin_amdgcn_readlane(bv, 8 * p + 6);
        int bB3 = __builtin_amdgcn_readlane(bv, 8 * p + 7);
        int dgA = __builtin_amdgcn_readlane(dgv, 2 * p);
        int dgB = __builtin_amdgcn_readlane(dgv, 2 * p + 1);
        float idA = 1.0f / (float)(dgA > 0 ? dgA : 1);
        float idB = 1.0f / (float)(dgB > 0 ? dgB : 1);
        int usA = x[nodeA * 64 + lane];               // self rows (early issue)
        int usB = x[nodeB * 64 + lane];
        f32x2 aA0 = {0.f, 0.f}, aA1 = aA0, aA2 = aA0;
        f32x2 aB0 = aA0, aB1 = aA0, aB2 = aA0;
        int eA = bA0, eB = bB0;
        unsigned qA0, qA1, qA2, qA3, qA4, qA5, qA6, qA7;
        unsigned qB0, qB1, qB2, qB3, qB4, qB5, qB6, qB7;
        if (eA < bA3) { LOADQ8(qA, eA) }
        if (eB < bB3) { LOADQ8(qB, eB) }
        while (true) {
            bool dA = eA < bA3, dB = eB < bB3;        // wave-uniform (SGPR bounds)
            if (!dA && !dB) break;
            int uA0, uA1, uA2, uA3, uA4, uA5, uA6, uA7;
            int uB0, uB1, uB2, uB3, uB4, uB5, uB6, uB7;
            if (dA) { LOADU8(uA, qA) }
            if (dB) { LOADU8(uB, qB) }
            // prefetch next 8 indices per active node (overread in slack;
            // values only register-copied, never dereferenced past loop exit)
            if (dA) { LOADQ8(qA, eA + 8) }
            if (dB) { LOADQ8(qB, eB + 8) }
            if (dA) {
                f32x2 s; SUM8(s, uA)
                if (eA < bA1)      aA0 += s;
                else if (eA < bA2) aA1 += s;
                else               aA2 += s;
                eA += 8;
            }
            if (dB) {
                f32x2 s; SUM8(s, uB)
                if (eB < bB1)      aB0 += s;
                else if (eB < bB2) aB1 += s;
                else               aB2 += s;
                eB += 8;
            }
        }
        uint32* arA = Alds + (wv * 4 + 2 * p) * ASTRIDE;
        uint32* arB = arA + ASTRIDE;
        f32x2 vsA = __builtin_amdgcn_cvt_pk_f32_fp8(usA, false);
        f32x2 vsB = __builtin_amdgcn_cvt_pk_f32_fp8(usB, false);
        arA[lane]       = pack2bf(make_float2(aA0.x * idA, aA0.y * idA));
        arA[64 + lane]  = pack2bf(make_float2(aA1.x * idA, aA1.y * idA));
        arA[128 + lane] = pack2bf(make_float2(aA2.x * idA, aA2.y * idA));
        arA[192 + lane] = pack2bf(make_float2(vsA.x, vsA.y));
        arB[lane]       = pack2bf(make_float2(aB0.x * idB, aB0.y * idB));
        arB[64 + lane]  = pack2bf(make_float2(aB1.x * idB, aB1.y * idB));
        arB[128 + lane] = pack2bf(make_float2(aB2.x * idB, aB2.y * idB));
        arB[192 + lane] = pack2bf(make_float2(vsB.x, vsB.y));
    }
    __syncthreads();

    // ---- phase B: MFMA GEMM (W = Whi + Wlo); wave w: n-tile w, m-tiles {0,1} ----
    f32x4 acc00 = {0.f, 0.f, 0.f, 0.f}, acc10 = acc00;
    int mrow0 = (lane & 15);
    int mrow1 = 16 + (lane & 15);
    int q4 = (lane >> 4) * 4;
    const bf16x8* wbh = (const bf16x8*)Wbh;
    const bf16x8* wbl = (const bf16x8*)Wbl;

#pragma unroll 4
    for (int kt = 0; kt < 16; kt++) {
        bf16x8 af0 = *(const bf16x8*)&Alds[mrow0 * ASTRIDE + kt * 16 + q4];
        bf16x8 af1 = *(const bf16x8*)&Alds[mrow1 * ASTRIDE + kt * 16 + q4];
        bf16x8 bh0 = wbh[(kt * 8 + wv) * 64 + lane];
        bf16x8 bl0 = wbl[(kt * 8 + wv) * 64 + lane];
        acc00 = __builtin_amdgcn_mfma_f32_16x16x32_bf16(af0, bh0, acc00, 0, 0, 0);
        acc10 = __builtin_amdgcn_mfma_f32_16x16x32_bf16(af1, bh0, acc10, 0, 0, 0);
        acc00 = __builtin_amdgcn_mfma_f32_16x16x32_bf16(af0, bl0, acc00, 0, 0, 0);
        acc10 = __builtin_amdgcn_mfma_f32_16x16x32_bf16(af1, bl0, acc10, 0, 0, 0);
    }
    __syncthreads();   // A-tile reads done; alias as hlds

    // ---- bias into LDS for LN stats ----
    float* hlds = (float*)Alds;            // [32][132]
    int n0 = wv * 16 + (lane & 15);
    float bj0 = lb[n0];
    int rbase = (lane >> 4) * 4;
#pragma unroll
    for (int r = 0; r < 4; r++) {
        hlds[(rbase + r) * 132 + n0]      = acc00[r] + bj0;
        hlds[(16 + rbase + r) * 132 + n0] = acc10[r] + bj0;
    }
    __syncthreads();

    {
        int node = tid >> 4, l16 = tid & 15;
        float s = 0.f, ss = 0.f;
#pragma unroll
        for (int i = 0; i < 8; i++) {
            float v = hlds[node * 132 + l16 + 16 * i];
            s += v; ss += v * v;
        }
        for (int d = 8; d >= 1; d >>= 1) {
            s += __shfl_down(s, d, 16);
            ss += __shfl_down(ss, d, 16);
        }
        if (l16 == 0) {
            float mu = s * (1.f / 128.f);
            float var = ss * (1.f / 128.f) - mu * mu;
            stat[node][0] = mu;
            stat[node][1] = rsqrtf(var + LNEPS);
        }
    }
    __syncthreads();

    // ---- LN epilogue: fp8 repack+store OR fused pool partial ----
    {
        int node = tid >> 4, q16 = tid & 15;
        float mu = stat[node][0], rs = stat[node][1];
        const float* hr = hlds + node * 132 + q16 * 8;
        float vv[8];
#pragma unroll
        for (int k = 0; k < 8; k++) {
            int f = q16 * 8 + k;
            vv[k] = (hr[k] - mu) * rs * g[f] + bta[f];
        }
        if (regW == nullptr) {
            int w[2];
#pragma unroll
            for (int p = 0; p < 2; p++) {
                int pk = __builtin_amdgcn_cvt_pk_fp8_f32(vv[p * 4 + 0], vv[p * 4 + 1], 0, false);
                pk = __builtin_amdgcn_cvt_pk_fp8_f32(vv[p * 4 + 2], vv[p * 4 + 3], pk, true);
                w[p] = pk;
            }
            *(int2*)(xout + (size_t)(nb + node) * 128 + q16 * 8) = make_int2(w[0], w[1]);
        } else {
            float s = 0.f;
#pragma unroll
            for (int k = 0; k < 8; k++) s += vv[k] * regW[q16 * 8 + k];
            for (int d = 32; d >= 1; d >>= 1) s += __shfl_down(s, d);
            if (lane == 0) red[wv] = s;
            __syncthreads();
            if (tid == 0) {
                partials[blockIdx.x] = red[0] + red[1] + red[2] + red[3] +
                                       red[4] + red[5] + red[6] + red[7];
            }
        }
    }
}

// ---------------- final reduction: 3125 partials -> scalar out ----------------

__global__ __launch_bounds__(1024) void k_red(const float* __restrict__ partials,
                                              const float* __restrict__ reg_b,
                                              float* __restrict__ out) {
    __shared__ float s[16];
    int tid = threadIdx.x;
    float v = 0.f;
    for (int i = tid; i < NBKT; i += 1024) v += partials[i];
    for (int d = 32; d >= 1; d >>= 1) v += __shfl_down(v, d);
    if ((tid & 63) == 0) s[tid >> 6] = v;
    __syncthreads();
    if (tid == 0) {
        float t = 0.f;
#pragma unroll
        for (int i = 0; i < 16; i++) t += s[i];
        out[0] = t * (1.0f / (float)NN) + reg_b[0];
    }
}

// ---------------- launcher ----------------

extern "C" void kernel_launch(void* const* d_in, const int* in_sizes, int n_in,
                              void* d_out, int out_size, void* d_ws, size_t ws_size,
                              hipStream_t stream) {
    const int*   z       = (const int*)d_in[0];
    const float* sd      = (const float*)d_in[1];
    const float* df      = (const float*)d_in[2];
    const float* cond    = (const float*)d_in[3];
    const float* mult    = (const float*)d_in[4];
    const int*   nt      = (const int*)d_in[5];
    const int*   ei      = (const int*)d_in[6];
    const int*   et      = (const int*)d_in[7];
    const float* z_embed = (const float*)d_in[8];
    const float* enc_W1  = (const float*)d_in[9];
    const float* enc_b1  = (const float*)d_in[10];
    const float* enc_W2  = (const float*)d_in[11];
    const float* enc_b2  = (const float*)d_in[12];
    const float* lin_W   = (const float*)d_in[13];
    const float* lin_b   = (const float*)d_in[14];
    const float* rel_W   = (const float*)d_in[15];
    const float* ln_g    = (const float*)d_in[16];
    const float* ln_b    = (const float*)d_in[17];
    const float* reg_W   = (const float*)d_in[18];
    const float* reg_b   = (const float*)d_in[19];
    float* out = (float*)d_out;

    char* p = (char*)d_ws;
    int* H          = (int*)p;      p += (size_t)PASSA_B * NBKT * 4;   // 3.2 MB
    int* btot       = (int*)p;      p += (size_t)4096 * 4;
    int* boff       = (int*)p;      p += (size_t)4096 * 4;
    int* misc       = (int*)p;      p += 16 * 4;
    float* partials = (float*)p;    p += (size_t)4096 * 4;
    int* off        = (int*)p;      p += (size_t)400384 * 4;
    int* degarr     = (int*)p;      p += (size_t)100096 * 4;
    ushort16* key16 = (ushort16*)p; p += (size_t)NE * 2;
    unsigned* hdr32 = (unsigned*)p; p += (size_t)NE * 4;
    unsigned* packed   = (unsigned*)p; p += (size_t)NE * 4;
    unsigned* packed2  = (unsigned*)p; p += (size_t)(NEP + 16) * 4;   // +16 dword prefetch slack
    unsigned* nodelist = (unsigned*)p; p += (size_t)NLIST2 * 4;
    ushort16* Wbh   = (ushort16*)p; p += (size_t)2 * 512 * 128 * 2;
    ushort16* Wbl   = (ushort16*)p; p += (size_t)2 * 512 * 128 * 2;
    ushort16* Weh   = (ushort16*)p; p += (size_t)65536 * 2;
    ushort16* Wel   = (ushort16*)p; p += (size_t)65536 * 2;
    ushort16* W1e   = (ushort16*)p; p += (size_t)32768 * 2;
    unsigned char* x0 = (unsigned char*)p; p += (size_t)(NN + 1) * HD;
    unsigned char* x1 = (unsigned char*)p; p += (size_t)(NN + 1) * HD;

    hipMemsetAsync(misc, 0, 64, stream);
    hipMemsetAsync(nodelist, 0xFF, (size_t)NLIST2 * 4, stream);

    k_hist<<<PASSA_B + WCATE_B + W1P_B + FILLN_B, 256, 0, stream>>>(
        ei, et, H, key16, hdr32, enc_W2, Weh, Wel, enc_W1, W1e,
        nt, misc, nodelist, (uint32*)x0, (uint32*)x1);
    k_s1<<<13, 256, 0, stream>>>(H, btot);
    k_s2<<<1, 1024, 0, stream>>>(btot, boff);
    k_fill2<<<FILL_B + WCAT_B + ENC_B, 256, 0, stream>>>(
        key16, hdr32, H, boff, packed,
        nodelist, z, sd, df, cond, mult, z_embed,
        W1e, enc_b1, enc_b2, x0,
        rel_W, lin_W, Wbh, Wbl, Weh, Wel);
    k_sort2<<<NBKT, 256, 0, stream>>>(packed, boff, packed2, off, degarr);

    // layer 0: x0 -> x1 (fp8 write)
    k_fused<<<NBKT, 512, 0, stream>>>((const ushort16*)x0, packed2, off, degarr,
                                      Wbh, Wbl,
                                      lin_b, ln_g, ln_b,
                                      x1, nullptr, partials);
    // layer 1: x1 -> per-block pool partials (x write skipped)
    k_fused<<<NBKT, 512, 0, stream>>>((const ushort16*)x1, packed2, off, degarr,
                                      Wbh + (size_t)512 * 128, Wbl + (size_t)512 * 128,
                                      lin_b + HD, ln_g + HD, ln_b + HD,
                                      x0, reg_W, partials);
    k_red<<<1, 1024, 0, stream>>>(partials, reg_b, out);
}